// Round 8
// baseline (42.316 us; speedup 1.0000x reference)
//
#include <hip/hip_runtime.h>

#define L_LAYERS 783
#define L_PAD    784           // = SEGF*GF = SEGS*GS
#define B_BATCH  8192
#define N_SITES  784
#define K_KRAUS  16

// FAST path geometry
#define SEGF     14
#define GF       56
// FALLBACK geometry (round-4 path, proven within 15 MB workspace)
#define SEGS     28
#define GS       28
#define TPBS     128

// ---------------------------------------------------------------------------
// Hermitian-reduced formulation.
// State v = (s00, s11, u, w), sigma = [[s00, u+iw], [u-iw, s11]].
// Per layer: v' = R v, R = C + D*xx0 + B*xx1 (D = A - C, since xx0+xx3 = 1),
// xx = outer(x,x)/|x|^2. Tc per layer: 48 floats = [C(16) | D(16) | B(16)].
// Pad layers (l >= 783): R = I  (C=I, D=0, B=0).
// ---------------------------------------------------------------------------
__global__ void __launch_bounds__(256)
build_T(const float* __restrict__ kr, const float* __restrict__ ki,
        float* __restrict__ Tc) {
    __shared__ float lr[K_KRAUS * 16];
    __shared__ float li[K_KRAUS * 16];
    __shared__ float gr[48], gi[48];
    int l = blockIdx.x;
    int t = threadIdx.x;
    float* o = Tc + (size_t)l * 48;

    if (l >= L_LAYERS) {                        // identity pad layer
        if (t < 16) {
            int row = t >> 2, col = t & 3;
            o[t]      = (row == col) ? 1.f : 0.f;
            o[16 + t] = 0.f;
            o[32 + t] = 0.f;
        }
        return;
    }

    lr[t] = kr[(size_t)l * 256 + t];
    li[t] = ki[(size_t)l * 256 + t];
    __syncthreads();

    if (t < 192) {
        int e = t >> 2, chunk = t & 3;
        int ci = e >> 4;                        // 0,1,2
        int c = ci >> 1, d = (ci + 1) >> 1;     // (0,0),(0,1),(1,1)
        int m = (e >> 2) & 3, q = e & 3;
        int i1 = m >> 1, j1 = m & 1, i2 = q >> 1, j2 = q & 1;
        int off1 = c * 4 + 2 * i1 + i2;
        int off2 = d * 4 + 2 * j1 + j2;
        float ar = 0.f, ai = 0.f;
        #pragma unroll
        for (int kk = 0; kk < 4; ++kk) {
            int kbase = (chunk * 4 + kk) * 16;
            #pragma unroll
            for (int a = 0; a < 2; ++a) {
                int x1 = kbase + a * 8 + off1;
                int x2 = kbase + a * 8 + off2;
                float k1r = lr[x1], k1i = li[x1];
                float k2r = lr[x2], k2i = li[x2];
                ar += k1r * k2r + k1i * k2i;    // K1 * conj(K2)
                ai += k1i * k2r - k1r * k2i;
            }
        }
        ar += __shfl_xor(ar, 1); ar += __shfl_xor(ar, 2);
        ai += __shfl_xor(ai, 1); ai += __shfl_xor(ai, 2);
        if (chunk == 0) { gr[e] = ar; gi[e] = ai; }
    }
    __syncthreads();

    if (t < 16) {
        int row = t >> 2, col = t & 3;
        int ci = (row == 0) ? 0 : (row == 1) ? 2 : 1;
        int base = ci * 16;
        float Ur[4], Ui[4];
        #pragma unroll
        for (int q = 0; q < 4; ++q) {
            if (col == 0)      { Ur[q] = gr[base + q];      Ui[q] = gi[base + q]; }
            else if (col == 1) { Ur[q] = gr[base + 12 + q]; Ui[q] = gi[base + 12 + q]; }
            else {
                float t1r = gr[base + 4 + q], t1i = gi[base + 4 + q];
                float t2r = gr[base + 8 + q], t2i = gi[base + 8 + q];
                if (col == 2) { Ur[q] = t1r + t2r;    Ui[q] = t1i + t2i; }
                else          { Ur[q] = -(t1i - t2i); Ui[q] = t1r - t2r; }   // i*(T1-T2)
            }
        }
        float A, Bc, Cc;
        if (row == 3) { A = Ui[0]; Bc = Ui[1] + Ui[2]; Cc = Ui[3]; }
        else          { A = Ur[0]; Bc = Ur[1] + Ur[2]; Cc = Ur[3]; }
        o[t]      = Cc;
        o[16 + t] = A - Cc;
        o[32 + t] = Bc;
    }
}

// ---------------------------------------------------------------------------
// FAST kernel 2: per (batch-chunk, segment) product of SEGF transfer matrices.
// Tc is WAVE-UNIFORM -> read straight from global (scalar s_load path, K$),
// no LDS staging for it. X staged through LDS in two 7-site phases
// (14.3 KB -> up to 11 blocks/CU; grid is 7/CU so all blocks resident).
// P stored SoA: P[(s*16 + i) * B + b].
// ---------------------------------------------------------------------------
__global__ void __launch_bounds__(256, 4)
seg_fused(const float* __restrict__ X, const float* __restrict__ Tc,
          float* __restrict__ P) {
    __shared__ float2 xxs[256 * 7];             // 14336 B
    int t  = threadIdx.x;
    int s  = blockIdx.y;
    int ls = s * SEGF;
    int b0 = blockIdx.x * 256;
    const float* tl0 = Tc + (size_t)ls * 48;    // wave-uniform base
    const float2* Xp = (const float2*)X;

    float pA[16], pB[16];
    #pragma unroll
    for (int i = 0; i < 16; ++i) pA[i] = (i % 5 == 0) ? 1.f : 0.f;

// stage 7 sites (half h) into xxs with coalesced idx%7 mapping
#define STAGE(H)                                                                \
    {                                                                           \
        _Pragma("unroll")                                                       \
        for (int e = 0; e < 7; ++e) {                                           \
            int idx  = t + e * 256;             /* 0..1791 */                   \
            int row  = idx / 7;                                                 \
            int col  = idx - row * 7;                                           \
            int site = ls + 1 + (H) * 7 + col;                                  \
            site = site < (N_SITES - 1) ? site : (N_SITES - 1);                 \
            float2 xv = Xp[(size_t)(b0 + row) * N_SITES + site];                \
            float inv = __builtin_amdgcn_rcpf(fmaf(xv.x, xv.x, xv.y * xv.y));   \
            xxs[row * 7 + col] = make_float2(xv.x * xv.x * inv,                 \
                                             xv.x * xv.y * inv);                \
        }                                                                       \
    }

#define STEP(SRC, DST, I, COL)                                                  \
    {                                                                           \
        const float* tl = tl0 + (I) * 48;       /* uniform -> s_load */         \
        float2 xx = xxs[t * 7 + (COL)];                                         \
        float R[16];                                                            \
        _Pragma("unroll")                                                       \
        for (int e = 0; e < 16; ++e)                                            \
            R[e] = fmaf(tl[32 + e], xx.y, fmaf(tl[16 + e], xx.x, tl[e]));       \
        _Pragma("unroll")                                                       \
        for (int r = 0; r < 4; ++r) {                                           \
            _Pragma("unroll")                                                   \
            for (int cc = 0; cc < 4; ++cc)                                      \
                DST[r * 4 + cc] =                                               \
                    fmaf(R[r * 4 + 0], SRC[cc],                                 \
                    fmaf(R[r * 4 + 1], SRC[4 + cc],                             \
                    fmaf(R[r * 4 + 2], SRC[8 + cc],                             \
                         R[r * 4 + 3] * SRC[12 + cc])));                        \
        }                                                                       \
    }

    // ---- half 0: layers ls+0 .. ls+6 ----
    STAGE(0);
    __syncthreads();
    STEP(pA, pB, 0, 0); STEP(pB, pA, 1, 1);
    STEP(pA, pB, 2, 2); STEP(pB, pA, 3, 3);
    STEP(pA, pB, 4, 4); STEP(pB, pA, 5, 5);
    STEP(pA, pB, 6, 6);                         // result in pB
    __syncthreads();                            // before restage

    // ---- half 1: layers ls+7 .. ls+13 ----
    STAGE(1);
    __syncthreads();
    STEP(pB, pA, 7, 0);  STEP(pA, pB, 8, 1);
    STEP(pB, pA, 9, 2);  STEP(pA, pB, 10, 3);
    STEP(pB, pA, 11, 4); STEP(pA, pB, 12, 5);
    STEP(pB, pA, 13, 6);                        // result in pA
#undef STEP
#undef STAGE

    int b = b0 + t;
    #pragma unroll
    for (int i = 0; i < 16; ++i)
        P[((size_t)(s * 16 + i)) * B_BATCH + b] = pA[i];
}

// ---------------------------------------------------------------------------
// FAST kernel 3: two-level combine for G=56 (8 groups x 7-chain, then 8-chain).
// ---------------------------------------------------------------------------
__global__ void __launch_bounds__(256)
combine56(const float* __restrict__ X, const float* __restrict__ P,
          float* __restrict__ out) {
    __shared__ float q[256][17];
    int t = threadIdx.x;
    int j = t >> 5, bl = t & 31;
    int b = blockIdx.x * 32 + bl;

    float qa[16], qb[16];
    #pragma unroll
    for (int i = 0; i < 16; ++i) qa[i] = (i % 5 == 0) ? 1.f : 0.f;

#define CSTEP(SRC, DST, K)                                                      \
    {                                                                           \
        float m[16];                                                            \
        _Pragma("unroll")                                                       \
        for (int i = 0; i < 16; ++i)                                            \
            m[i] = P[((size_t)((j * 7 + (K)) * 16 + i)) * B_BATCH + b];         \
        _Pragma("unroll")                                                       \
        for (int r = 0; r < 4; ++r) {                                           \
            _Pragma("unroll")                                                   \
            for (int cc = 0; cc < 4; ++cc)                                      \
                DST[r * 4 + cc] =                                               \
                    fmaf(m[r * 4 + 0], SRC[cc],                                 \
                    fmaf(m[r * 4 + 1], SRC[4 + cc],                             \
                    fmaf(m[r * 4 + 2], SRC[8 + cc],                             \
                         m[r * 4 + 3] * SRC[12 + cc])));                        \
        }                                                                       \
    }
    CSTEP(qa, qb, 0); CSTEP(qb, qa, 1);
    CSTEP(qa, qb, 2); CSTEP(qb, qa, 3);
    CSTEP(qa, qb, 4); CSTEP(qb, qa, 5);
    CSTEP(qa, qb, 6);                          // result in qb
#undef CSTEP

    #pragma unroll
    for (int i = 0; i < 16; ++i) q[t][i] = qb[i];
    __syncthreads();

    if (t < 32) {
        int b2 = blockIdx.x * 32 + t;
        const float2* Xp = (const float2*)X;
        float2 xv = Xp[(size_t)b2 * N_SITES];
        float inv = __builtin_amdgcn_rcpf(fmaf(xv.x, xv.x, xv.y * xv.y));
        float v0 = xv.x * xv.x * inv;
        float v1 = xv.y * xv.y * inv;
        float v2 = xv.x * xv.y * inv;
        float v3 = 0.f;
        #pragma unroll
        for (int jj = 0; jj < 8; ++jj) {
            const float* qq = q[jj * 32 + t];
            float n0 = fmaf(qq[0],  v0, fmaf(qq[1],  v1, fmaf(qq[2],  v2, qq[3]  * v3)));
            float n1 = fmaf(qq[4],  v0, fmaf(qq[5],  v1, fmaf(qq[6],  v2, qq[7]  * v3)));
            float n2 = fmaf(qq[8],  v0, fmaf(qq[9],  v1, fmaf(qq[10], v2, qq[11] * v3)));
            float n3 = fmaf(qq[12], v0, fmaf(qq[13], v1, fmaf(qq[14], v2, qq[15] * v3)));
            v0 = n0; v1 = n1; v2 = n2; v3 = n3;
        }
        out[b2] = v0;
    }
}

// ---------------------------------------------------------------------------
// FALLBACK kernels (round-4 path, proven within 15 MB workspace)
// ---------------------------------------------------------------------------
__global__ void __launch_bounds__(TPBS)
seg_slow(const float* __restrict__ X, const float* __restrict__ Tc,
         float* __restrict__ P) {
    __shared__ float4 tcs4[SEGS * 12];
    __shared__ float2 xxs[TPBS][SEGS + 1];
    int t  = threadIdx.x;
    int s  = blockIdx.y;
    int ls = s * SEGS;
    int b0 = blockIdx.x * TPBS;

    const float4* tg = (const float4*)Tc + (size_t)ls * 12;
    #pragma unroll
    for (int i = t; i < SEGS * 12; i += TPBS) tcs4[i] = tg[i];

    const float2* Xp = (const float2*)X;
    for (int idx = t; idx < SEGS * TPBS; idx += TPBS) {
        int col  = idx % SEGS;
        int row  = idx / SEGS;
        int site = ls + 1 + col;
        site = site < (N_SITES - 1) ? site : (N_SITES - 1);
        float2 xv = Xp[(size_t)(b0 + row) * N_SITES + site];
        float inv = __builtin_amdgcn_rcpf(fmaf(xv.x, xv.x, xv.y * xv.y));
        xxs[row][col] = make_float2(xv.x * xv.x * inv, xv.x * xv.y * inv);
    }
    __syncthreads();

    float pA[16], pB[16];
    #pragma unroll
    for (int i = 0; i < 16; ++i) pA[i] = (i % 5 == 0) ? 1.f : 0.f;

#define STEP(SRC, DST, I)                                                       \
    {                                                                           \
        float2 xx = xxs[t][I];                                                  \
        float R[16];                                                            \
        _Pragma("unroll")                                                       \
        for (int r = 0; r < 4; ++r) {                                           \
            float4 cv = tcs4[(I) * 12 + r];                                     \
            float4 dv = tcs4[(I) * 12 + 4 + r];                                 \
            float4 bv = tcs4[(I) * 12 + 8 + r];                                 \
            R[r * 4 + 0] = fmaf(bv.x, xx.y, fmaf(dv.x, xx.x, cv.x));            \
            R[r * 4 + 1] = fmaf(bv.y, xx.y, fmaf(dv.y, xx.x, cv.y));            \
            R[r * 4 + 2] = fmaf(bv.z, xx.y, fmaf(dv.z, xx.x, cv.z));            \
            R[r * 4 + 3] = fmaf(bv.w, xx.y, fmaf(dv.w, xx.x, cv.w));            \
        }                                                                       \
        _Pragma("unroll")                                                       \
        for (int r = 0; r < 4; ++r) {                                           \
            _Pragma("unroll")                                                   \
            for (int cc = 0; cc < 4; ++cc)                                      \
                DST[r * 4 + cc] =                                               \
                    fmaf(R[r * 4 + 0], SRC[cc],                                 \
                    fmaf(R[r * 4 + 1], SRC[4 + cc],                             \
                    fmaf(R[r * 4 + 2], SRC[8 + cc],                             \
                         R[r * 4 + 3] * SRC[12 + cc])));                        \
        }                                                                       \
    }

    #pragma unroll
    for (int i = 0; i < SEGS; i += 2) {
        STEP(pA, pB, i);
        STEP(pB, pA, i + 1);
    }
#undef STEP

    int b = b0 + t;
    #pragma unroll
    for (int i = 0; i < 16; ++i)
        P[((size_t)(s * 16 + i)) * B_BATCH + b] = pA[i];
}

__global__ void __launch_bounds__(256)
combine28(const float* __restrict__ X, const float* __restrict__ P,
          float* __restrict__ out) {
    __shared__ float q[256][17];
    int t  = threadIdx.x;
    int j  = t >> 6;
    int bl = t & 63;
    int b  = blockIdx.x * 64 + bl;

    float qa[16], qb[16];
    #pragma unroll
    for (int i = 0; i < 16; ++i) qa[i] = (i % 5 == 0) ? 1.f : 0.f;

#define CSTEP(SRC, DST, K)                                                      \
    {                                                                           \
        float m[16];                                                            \
        _Pragma("unroll")                                                       \
        for (int i = 0; i < 16; ++i)                                            \
            m[i] = P[((size_t)((j * 7 + (K)) * 16 + i)) * B_BATCH + b];         \
        _Pragma("unroll")                                                       \
        for (int r = 0; r < 4; ++r) {                                           \
            _Pragma("unroll")                                                   \
            for (int cc = 0; cc < 4; ++cc)                                      \
                DST[r * 4 + cc] =                                               \
                    fmaf(m[r * 4 + 0], SRC[cc],                                 \
                    fmaf(m[r * 4 + 1], SRC[4 + cc],                             \
                    fmaf(m[r * 4 + 2], SRC[8 + cc],                             \
                         m[r * 4 + 3] * SRC[12 + cc])));                        \
        }                                                                       \
    }
    CSTEP(qa, qb, 0); CSTEP(qb, qa, 1);
    CSTEP(qa, qb, 2); CSTEP(qb, qa, 3);
    CSTEP(qa, qb, 4); CSTEP(qb, qa, 5);
    CSTEP(qa, qb, 6);
#undef CSTEP

    #pragma unroll
    for (int i = 0; i < 16; ++i) q[t][i] = qb[i];
    __syncthreads();

    if (t < 64) {
        int b2 = blockIdx.x * 64 + t;
        const float2* Xp = (const float2*)X;
        float2 xv = Xp[(size_t)b2 * N_SITES];
        float inv = __builtin_amdgcn_rcpf(fmaf(xv.x, xv.x, xv.y * xv.y));
        float v0 = xv.x * xv.x * inv;
        float v1 = xv.y * xv.y * inv;
        float v2 = xv.x * xv.y * inv;
        float v3 = 0.f;
        #pragma unroll
        for (int jj = 0; jj < 4; ++jj) {
            const float* qq = q[jj * 64 + t];
            float n0 = fmaf(qq[0],  v0, fmaf(qq[1],  v1, fmaf(qq[2],  v2, qq[3]  * v3)));
            float n1 = fmaf(qq[4],  v0, fmaf(qq[5],  v1, fmaf(qq[6],  v2, qq[7]  * v3)));
            float n2 = fmaf(qq[8],  v0, fmaf(qq[9],  v1, fmaf(qq[10], v2, qq[11] * v3)));
            float n3 = fmaf(qq[12], v0, fmaf(qq[13], v1, fmaf(qq[14], v2, qq[15] * v3)));
            v0 = n0; v1 = n1; v2 = n2; v3 = n3;
        }
        out[b2] = v0;
    }
}

// ---------------------------------------------------------------------------
extern "C" void kernel_launch(void* const* d_in, const int* in_sizes, int n_in,
                              void* d_out, int out_size, void* d_ws, size_t ws_size,
                              hipStream_t stream) {
    const float* X  = (const float*)d_in[0];
    const float* kr = (const float*)d_in[1];
    const float* ki = (const float*)d_in[2];
    float* out = (float*)d_out;

    float* Tc = (float*)d_ws;
    const size_t Tb  = (size_t)L_PAD * 48 * sizeof(float);         // 150,528 (256-mult)
    const size_t Pfb = (size_t)GF * 16 * B_BATCH * sizeof(float);  // 29,360,128

    build_T<<<L_PAD, 256, 0, stream>>>(kr, ki, Tc);

    if (ws_size >= Tb + Pfb) {
        // FAST path: fused stage+product, scalar-path Tc, 2-phase X staging
        float* P = (float*)((char*)d_ws + Tb);
        dim3 gs(B_BATCH / 256, GF);
        seg_fused<<<gs, 256, 0, stream>>>(X, Tc, P);
        combine56<<<B_BATCH / 32, 256, 0, stream>>>(X, P, out);
    } else {
        // FALLBACK (round-4 path, 14.8 MB)
        float* P = (float*)((char*)d_ws + Tb);
        dim3 gs(B_BATCH / TPBS, GS);
        seg_slow<<<gs, TPBS, 0, stream>>>(X, Tc, P);
        combine28<<<B_BATCH / 64, 256, 0, stream>>>(X, P, out);
    }
}